// Round 1
// baseline (7691.455 us; speedup 1.0000x reference)
//
#include <hip/hip_runtime.h>
#include <math.h>

// Problem constants (match reference)
#define NN 150000
#define NE 2400000
#define NG 1024
#define DIN 6
#define DH 32
#define DB 16
#define BN_EPS 1e-5f

// ---------------- edge scatter: layer 1 (6 channels) ----------------
__global__ void edge_scatter6(const int* __restrict__ ei,
                              const float* __restrict__ x,
                              float* __restrict__ agg) {
    int e = blockIdx.x * blockDim.x + threadIdx.x;
    if (e >= NE) return;
    int s = ei[e];
    int d = ei[NE + e];
    const float* xs = x + (long)s * DIN;
    float* ad = agg + (long)d * DIN;
#pragma unroll
    for (int k = 0; k < DIN; ++k) atomicAdd(ad + k, xs[k]);
}

// ---------------- edge scatter: 32 channels (4 threads/edge x 8ch) ----------------
__global__ void edge_scatter32(const int* __restrict__ ei,
                               const float* __restrict__ h,
                               float* __restrict__ agg) {
    long tid = (long)blockIdx.x * blockDim.x + threadIdx.x;
    int e = (int)(tid >> 2);
    int g = (int)(tid & 3);
    if (e >= NE) return;
    int s = ei[e];
    int d = ei[NE + e];
    const float4* hs = (const float4*)(h + (long)s * DH + g * 8);
    float4 a = hs[0];
    float4 b = hs[1];
    float* ad = agg + (long)d * DH + g * 8;
    atomicAdd(ad + 0, a.x); atomicAdd(ad + 1, a.y);
    atomicAdd(ad + 2, a.z); atomicAdd(ad + 3, a.w);
    atomicAdd(ad + 4, b.x); atomicAdd(ad + 5, b.y);
    atomicAdd(ad + 6, b.z); atomicAdd(ad + 7, b.w);
}

// ---------------- fused MLP (IN->32 relu ->32) + relu + BN-stat accumulation ----------------
template <int IN>
__global__ void mlp_stats(const float* __restrict__ agg,
                          float* __restrict__ out,
                          const float* __restrict__ w1, const float* __restrict__ b1,
                          const float* __restrict__ w2, const float* __restrict__ b2,
                          float* __restrict__ stats /* [64]: sum[32], sumsq[32] */) {
    __shared__ float sw1[IN * DH];
    __shared__ float sw2[DH * DH];
    __shared__ float sb1[DH];
    __shared__ float sb2[DH];
    int t = threadIdx.x;
    for (int i = t; i < IN * DH; i += blockDim.x) sw1[i] = w1[i];
    for (int i = t; i < DH * DH; i += blockDim.x) sw2[i] = w2[i];
    if (t < DH) { sb1[t] = b1[t]; sb2[t] = b2[t]; }
    __syncthreads();

    int node = blockIdx.x * blockDim.x + t;
    bool valid = node < NN;

    float a[IN];
    if (valid) {
        const float* ar = agg + (long)node * IN;
#pragma unroll
        for (int k = 0; k < IN; ++k) a[k] = ar[k];
    } else {
#pragma unroll
        for (int k = 0; k < IN; ++k) a[k] = 0.f;
    }

    float u[DH];
#pragma unroll
    for (int j = 0; j < DH; ++j) {
        float acc = sb1[j];
#pragma unroll
        for (int k = 0; k < IN; ++k) acc += a[k] * sw1[k * DH + j];
        u[j] = fmaxf(acc, 0.f);
    }

    float r[DH];
#pragma unroll
    for (int j = 0; j < DH; ++j) {
        float acc = sb2[j];
#pragma unroll
        for (int k = 0; k < DH; ++k) acc += u[k] * sw2[k * DH + j];
        r[j] = valid ? fmaxf(acc, 0.f) : 0.f;
    }

    if (valid) {
        float4* o = (float4*)(out + (long)node * DH);
#pragma unroll
        for (int q = 0; q < DH / 4; ++q)
            o[q] = make_float4(r[4 * q], r[4 * q + 1], r[4 * q + 2], r[4 * q + 3]);
    }

    // per-channel sum / sumsq, wave-reduced then one atomic per wave
    int lane = t & 63;
#pragma unroll
    for (int j = 0; j < DH; ++j) {
        float s = r[j];
        float q = r[j] * r[j];
        for (int o = 32; o > 0; o >>= 1) {
            s += __shfl_xor(s, o);
            q += __shfl_xor(q, o);
        }
        if (lane == 0) {
            atomicAdd(&stats[j], s);
            atomicAdd(&stats[DH + j], q);
        }
    }
}

// ---------------- BN apply (in place) ----------------
__global__ void bn_apply(float* __restrict__ h,
                         const float* __restrict__ stats,
                         const float* __restrict__ g,
                         const float* __restrict__ be) {
    long tid = (long)blockIdx.x * blockDim.x + threadIdx.x;
    if (tid >= (long)NN * DH) return;
    int d = (int)(tid & (DH - 1));
    float mu = stats[d] * (1.0f / NN);
    float var = stats[DH + d] * (1.0f / NN) - mu * mu;
    float sc = g[d] * rsqrtf(var + BN_EPS);
    h[tid] = (h[tid] - mu) * sc + be[d];
}

// ---------------- global mean pool (atomic) ----------------
__global__ void pool_kernel(const float* __restrict__ h,
                            const int* __restrict__ batch,
                            float* __restrict__ sums,
                            float* __restrict__ cnt) {
    long tid = (long)blockIdx.x * blockDim.x + threadIdx.x;
    if (tid >= (long)NN * DH) return;
    int node = (int)(tid >> 5);
    int d = (int)(tid & 31);
    int b = batch[node];
    atomicAdd(&sums[(long)b * DH + d], h[tid]);
    if (d == 0) atomicAdd(&cnt[b], 1.0f);
}

// ---------------- head: emb -> 16 relu -> 1 sigmoid ----------------
__global__ void head_kernel(const float* __restrict__ sums,
                            const float* __restrict__ cnt,
                            const float* __restrict__ wb, const float* __restrict__ bb,
                            const float* __restrict__ wm, const float* __restrict__ bm,
                            float* __restrict__ out) {
    __shared__ float swb[DH * DB];
    __shared__ float sbb[DB];
    __shared__ float swm[DB];
    int t = threadIdx.x;
    for (int i = t; i < DH * DB; i += blockDim.x) swb[i] = wb[i];
    if (t < DB) { sbb[t] = bb[t]; swm[t] = wm[t]; }
    __syncthreads();

    int g = blockIdx.x * blockDim.x + t;
    if (g >= NG) return;
    float c = fmaxf(cnt[g], 1.0f);
    float inv = 1.0f / c;
    float emb[DH];
#pragma unroll
    for (int d = 0; d < DH; ++d) emb[d] = sums[(long)g * DH + d] * inv;
    float acc = bm[0];
#pragma unroll
    for (int j = 0; j < DB; ++j) {
        float z = sbb[j];
#pragma unroll
        for (int d = 0; d < DH; ++d) z += emb[d] * swb[d * DB + j];
        z = fmaxf(z, 0.f);
        acc += z * swm[j];
    }
    out[g] = 1.0f / (1.0f + expf(-acc));
}

extern "C" void kernel_launch(void* const* d_in, const int* in_sizes, int n_in,
                              void* d_out, int out_size, void* d_ws, size_t ws_size,
                              hipStream_t stream) {
    const float* x   = (const float*)d_in[0];
    const int*   ei  = (const int*)d_in[1];
    const int*   bat = (const int*)d_in[2];
    const float* w1a = (const float*)d_in[3];  const float* b1a = (const float*)d_in[4];
    const float* w1b = (const float*)d_in[5];  const float* b1b = (const float*)d_in[6];
    const float* g1  = (const float*)d_in[7];  const float* be1 = (const float*)d_in[8];
    const float* w2a = (const float*)d_in[9];  const float* b2a = (const float*)d_in[10];
    const float* w2b = (const float*)d_in[11]; const float* b2b = (const float*)d_in[12];
    const float* g2  = (const float*)d_in[13]; const float* be2 = (const float*)d_in[14];
    const float* w3a = (const float*)d_in[15]; const float* b3a = (const float*)d_in[16];
    const float* w3b = (const float*)d_in[17]; const float* b3b = (const float*)d_in[18];
    const float* g3  = (const float*)d_in[19]; const float* be3 = (const float*)d_in[20];
    const float* wb  = (const float*)d_in[21]; const float* bb  = (const float*)d_in[22];
    const float* wm  = (const float*)d_in[23]; const float* bm  = (const float*)d_in[24];
    float* out = (float*)d_out;

    // workspace layout (floats)
    float* ws = (float*)d_ws;
    float* hbuf   = ws;                       // NN*DH
    float* aggbuf = hbuf + (long)NN * DH;     // NN*DH (layer1 uses first NN*DIN)
    float* stats1 = aggbuf + (long)NN * DH;   // 64
    float* stats2 = stats1 + 2 * DH;          // 64
    float* stats3 = stats2 + 2 * DH;          // 64
    float* psums  = stats3 + 2 * DH;          // NG*DH
    float* pcnt   = psums + (long)NG * DH;    // NG
    size_t zero_bytes = (3 * 2 * DH + (long)NG * DH + NG) * sizeof(float);

    hipMemsetAsync(stats1, 0, zero_bytes, stream);

    const int B = 256;
    int blkN   = (NN + B - 1) / B;
    int blkNDH = (int)(((long)NN * DH + B - 1) / B);
    int blkE   = (NE + B - 1) / B;
    int blkE4  = (int)(((long)NE * 4 + B - 1) / B);

    // ---- layer 1 ----
    hipMemcpyAsync(aggbuf, x, (long)NN * DIN * sizeof(float), hipMemcpyDeviceToDevice, stream);
    edge_scatter6<<<blkE, B, 0, stream>>>(ei, x, aggbuf);
    mlp_stats<DIN><<<blkN, B, 0, stream>>>(aggbuf, hbuf, w1a, b1a, w1b, b1b, stats1);
    bn_apply<<<blkNDH, B, 0, stream>>>(hbuf, stats1, g1, be1);

    // ---- layer 2 ----
    hipMemcpyAsync(aggbuf, hbuf, (long)NN * DH * sizeof(float), hipMemcpyDeviceToDevice, stream);
    edge_scatter32<<<blkE4, B, 0, stream>>>(ei, hbuf, aggbuf);
    mlp_stats<DH><<<blkN, B, 0, stream>>>(aggbuf, hbuf, w2a, b2a, w2b, b2b, stats2);
    bn_apply<<<blkNDH, B, 0, stream>>>(hbuf, stats2, g2, be2);

    // ---- layer 3 ----
    hipMemcpyAsync(aggbuf, hbuf, (long)NN * DH * sizeof(float), hipMemcpyDeviceToDevice, stream);
    edge_scatter32<<<blkE4, B, 0, stream>>>(ei, hbuf, aggbuf);
    mlp_stats<DH><<<blkN, B, 0, stream>>>(aggbuf, hbuf, w3a, b3a, w3b, b3b, stats3);
    bn_apply<<<blkNDH, B, 0, stream>>>(hbuf, stats3, g3, be3);

    // ---- pool + head ----
    pool_kernel<<<blkNDH, B, 0, stream>>>(hbuf, bat, psums, pcnt);
    head_kernel<<<(NG + B - 1) / B, B, 0, stream>>>(psums, pcnt, wb, bb, wm, bm, out);
}

// Round 2
// 2792.039 us; speedup vs baseline: 2.7548x; 2.7548x over previous
//
#include <hip/hip_runtime.h>
#include <math.h>

// Problem constants (match reference)
#define NN 150000
#define NE 2400000
#define NG 1024
#define DIN 6
#define DH 32
#define DB 16
#define BN_EPS 1e-5f

#define NCHUNK ((NN + 1023) / 1024)   // 147

// ================= CSR build =================
__global__ void deg_hist(const int* __restrict__ ei, int* __restrict__ deg) {
    int e = blockIdx.x * blockDim.x + threadIdx.x;
    if (e >= NE) return;
    atomicAdd(&deg[ei[NE + e]], 1);
}

__global__ void ghist_kernel(const int* __restrict__ bat, int* __restrict__ gh) {
    int n = blockIdx.x * blockDim.x + threadIdx.x;
    if (n >= NN) return;
    atomicAdd(&gh[bat[n]], 1);
}

// per-chunk (1024 elems) sums of deg
__global__ void chunk_reduce(const int* __restrict__ deg, int* __restrict__ csum) {
    __shared__ int sd[256];
    int c = blockIdx.x, t = threadIdx.x;
    int base = c * 1024;
    int v = 0;
    for (int i = t; i < 1024; i += 256) {
        int idx = base + i;
        if (idx < NN) v += deg[idx];
    }
    sd[t] = v;
    __syncthreads();
    for (int s = 128; s > 0; s >>= 1) {
        if (t < s) sd[t] += sd[t + s];
        __syncthreads();
    }
    if (t == 0) csum[c] = sd[0];
}

// single-block exclusive scan of chunk sums (NCHUNK <= 256); also row_ptr[NN]=NE
__global__ void scan_chunks(int* __restrict__ csum, int* __restrict__ row_ptr) {
    __shared__ int s[256];
    int t = threadIdx.x;
    s[t] = (t < NCHUNK) ? csum[t] : 0;
    __syncthreads();
    for (int off = 1; off < 256; off <<= 1) {
        int val = (t >= off) ? s[t - off] : 0;
        __syncthreads();
        s[t] += val;
        __syncthreads();
    }
    if (t < NCHUNK) csum[t] = (t == 0) ? 0 : s[t - 1];
    if (t == 0) row_ptr[NN] = NE;
}

// per-chunk exclusive scan -> row_ptr + cursor copy
__global__ void chunk_scan(const int* __restrict__ deg, const int* __restrict__ cbase,
                           int* __restrict__ row_ptr, int* __restrict__ cursor) {
    __shared__ int s[256];
    int c = blockIdx.x, t = threadIdx.x;
    int idx = c * 1024 + t * 4;
    int v0 = 0, v1 = 0, v2 = 0, v3 = 0;
    if (idx + 0 < NN) v0 = deg[idx + 0];
    if (idx + 1 < NN) v1 = deg[idx + 1];
    if (idx + 2 < NN) v2 = deg[idx + 2];
    if (idx + 3 < NN) v3 = deg[idx + 3];
    int sum = v0 + v1 + v2 + v3;
    s[t] = sum;
    __syncthreads();
    for (int off = 1; off < 256; off <<= 1) {
        int val = (t >= off) ? s[t - off] : 0;
        __syncthreads();
        s[t] += val;
        __syncthreads();
    }
    int run = cbase[c] + s[t] - sum;
    if (idx + 0 < NN) { row_ptr[idx + 0] = run; cursor[idx + 0] = run; run += v0; }
    if (idx + 1 < NN) { row_ptr[idx + 1] = run; cursor[idx + 1] = run; run += v1; }
    if (idx + 2 < NN) { row_ptr[idx + 2] = run; cursor[idx + 2] = run; run += v2; }
    if (idx + 3 < NN) { row_ptr[idx + 3] = run; cursor[idx + 3] = run; run += v3; }
}

// single-block exclusive scan of graph hist (1024 = 256*4); gptr[NG]=NN
__global__ void gscan(const int* __restrict__ gh, int* __restrict__ gptr) {
    __shared__ int s[256];
    int t = threadIdx.x;
    int idx = t * 4;
    int v0 = gh[idx + 0], v1 = gh[idx + 1], v2 = gh[idx + 2], v3 = gh[idx + 3];
    int sum = v0 + v1 + v2 + v3;
    s[t] = sum;
    __syncthreads();
    for (int off = 1; off < 256; off <<= 1) {
        int val = (t >= off) ? s[t - off] : 0;
        __syncthreads();
        s[t] += val;
        __syncthreads();
    }
    int run = s[t] - sum;
    gptr[idx + 0] = run; run += v0;
    gptr[idx + 1] = run; run += v1;
    gptr[idx + 2] = run; run += v2;
    gptr[idx + 3] = run;
    if (t == 0) gptr[NG] = NN;
}

__global__ void fill_csr(const int* __restrict__ ei, int* __restrict__ cursor,
                         int* __restrict__ csr_src) {
    int e = blockIdx.x * blockDim.x + threadIdx.x;
    if (e >= NE) return;
    int s = ei[e];
    int d = ei[NE + e];
    int slot = atomicAdd(&cursor[d], 1);
    csr_src[slot] = s;
}

// ================= gather aggregation =================
// layer 1: 6 channels, 1 thread per node (3x float2 per edge)
__global__ void gather6(const int* __restrict__ row_ptr, const int* __restrict__ csr_src,
                        const float* __restrict__ x, float* __restrict__ agg) {
    int node = blockIdx.x * blockDim.x + threadIdx.x;
    if (node >= NN) return;
    int beg = row_ptr[node], end = row_ptr[node + 1];
    const float2* xs = (const float2*)(x + (long)node * DIN);
    float2 a0 = xs[0], a1 = xs[1], a2 = xs[2];   // self term
    for (int e = beg; e < end; ++e) {
        int s = csr_src[e];
        const float2* p = (const float2*)(x + (long)s * DIN);
        float2 b0 = p[0], b1 = p[1], b2 = p[2];
        a0.x += b0.x; a0.y += b0.y;
        a1.x += b1.x; a1.y += b1.y;
        a2.x += b2.x; a2.y += b2.y;
    }
    float2* o = (float2*)(agg + (long)node * DIN);
    o[0] = a0; o[1] = a1; o[2] = a2;
}

// layers 2/3: 32 channels, 8 threads per node (float4 each)
__global__ void gather32(const int* __restrict__ row_ptr, const int* __restrict__ csr_src,
                         const float* __restrict__ h, float* __restrict__ agg) {
    long tid = (long)blockIdx.x * blockDim.x + threadIdx.x;
    int node = (int)(tid >> 3);
    int t = (int)(tid & 7);
    if (node >= NN) return;
    int beg = row_ptr[node], end = row_ptr[node + 1];
    const float4* self = (const float4*)(h + (long)node * DH) + t;
    float4 acc = *self;
    for (int e = beg; e < end; ++e) {
        int s = csr_src[e];
        float4 v = *((const float4*)(h + (long)s * DH) + t);
        acc.x += v.x; acc.y += v.y; acc.z += v.z; acc.w += v.w;
    }
    *((float4*)(agg + (long)node * DH) + t) = acc;
}

// ================= fused MLP + relu + BN-stat accumulation =================
template <int IN>
__global__ void mlp_stats(const float* __restrict__ agg,
                          float* __restrict__ out,
                          const float* __restrict__ w1, const float* __restrict__ b1,
                          const float* __restrict__ w2, const float* __restrict__ b2,
                          float* __restrict__ stats /* [64]: sum[32], sumsq[32] */) {
    __shared__ float sw1[IN * DH];
    __shared__ float sw2[DH * DH];
    __shared__ float sb1[DH];
    __shared__ float sb2[DH];
    int t = threadIdx.x;
    for (int i = t; i < IN * DH; i += blockDim.x) sw1[i] = w1[i];
    for (int i = t; i < DH * DH; i += blockDim.x) sw2[i] = w2[i];
    if (t < DH) { sb1[t] = b1[t]; sb2[t] = b2[t]; }
    __syncthreads();

    int node = blockIdx.x * blockDim.x + t;
    bool valid = node < NN;

    float a[IN];
    if (valid) {
        const float* ar = agg + (long)node * IN;
#pragma unroll
        for (int k = 0; k < IN; ++k) a[k] = ar[k];
    } else {
#pragma unroll
        for (int k = 0; k < IN; ++k) a[k] = 0.f;
    }

    float u[DH];
#pragma unroll
    for (int j = 0; j < DH; ++j) {
        float acc = sb1[j];
#pragma unroll
        for (int k = 0; k < IN; ++k) acc += a[k] * sw1[k * DH + j];
        u[j] = fmaxf(acc, 0.f);
    }

    float r[DH];
#pragma unroll
    for (int j = 0; j < DH; ++j) {
        float acc = sb2[j];
#pragma unroll
        for (int k = 0; k < DH; ++k) acc += u[k] * sw2[k * DH + j];
        r[j] = valid ? fmaxf(acc, 0.f) : 0.f;
    }

    if (valid) {
        float4* o = (float4*)(out + (long)node * DH);
#pragma unroll
        for (int q = 0; q < DH / 4; ++q)
            o[q] = make_float4(r[4 * q], r[4 * q + 1], r[4 * q + 2], r[4 * q + 3]);
    }

    int lane = t & 63;
#pragma unroll
    for (int j = 0; j < DH; ++j) {
        float s = r[j];
        float q = r[j] * r[j];
        for (int o = 32; o > 0; o >>= 1) {
            s += __shfl_xor(s, o);
            q += __shfl_xor(q, o);
        }
        if (lane == 0) {
            atomicAdd(&stats[j], s);
            atomicAdd(&stats[DH + j], q);
        }
    }
}

// ================= BN apply (in place) =================
__global__ void bn_apply(float* __restrict__ h,
                         const float* __restrict__ stats,
                         const float* __restrict__ g,
                         const float* __restrict__ be) {
    long tid = (long)blockIdx.x * blockDim.x + threadIdx.x;
    if (tid >= (long)NN * DH) return;
    int d = (int)(tid & (DH - 1));
    float mu = stats[d] * (1.0f / NN);
    float var = stats[DH + d] * (1.0f / NN) - mu * mu;
    float sc = g[d] * rsqrtf(var + BN_EPS);
    h[tid] = (h[tid] - mu) * sc + be[d];
}

// ================= per-graph mean pool (no atomics; batch is sorted) =================
__global__ void pool2(const float* __restrict__ h, const int* __restrict__ gptr,
                      float* __restrict__ emb) {
    int g = blockIdx.x;
    int t = threadIdx.x;           // 64 threads
    int beg = gptr[g], end = gptr[g + 1];
    int d = t & 31, half = t >> 5;
    float acc = 0.f;
    for (int n = beg + half; n < end; n += 2) acc += h[(long)n * DH + d];
    acc += __shfl_xor(acc, 32);
    if (t < 32) {
        float cnt = (float)(end - beg);
        emb[(long)g * DH + d] = acc / fmaxf(cnt, 1.0f);
    }
}

// ================= head: emb -> 16 relu -> 1 sigmoid =================
__global__ void head_kernel(const float* __restrict__ emb,
                            const float* __restrict__ wb, const float* __restrict__ bb,
                            const float* __restrict__ wm, const float* __restrict__ bm,
                            float* __restrict__ out) {
    __shared__ float swb[DH * DB];
    __shared__ float sbb[DB];
    __shared__ float swm[DB];
    int t = threadIdx.x;
    for (int i = t; i < DH * DB; i += blockDim.x) swb[i] = wb[i];
    if (t < DB) { sbb[t] = bb[t]; swm[t] = wm[t]; }
    __syncthreads();

    int g = blockIdx.x * blockDim.x + t;
    if (g >= NG) return;
    float e[DH];
#pragma unroll
    for (int d = 0; d < DH; ++d) e[d] = emb[(long)g * DH + d];
    float acc = bm[0];
#pragma unroll
    for (int j = 0; j < DB; ++j) {
        float z = sbb[j];
#pragma unroll
        for (int d = 0; d < DH; ++d) z += e[d] * swb[d * DB + j];
        z = fmaxf(z, 0.f);
        acc += z * swm[j];
    }
    out[g] = 1.0f / (1.0f + expf(-acc));
}

extern "C" void kernel_launch(void* const* d_in, const int* in_sizes, int n_in,
                              void* d_out, int out_size, void* d_ws, size_t ws_size,
                              hipStream_t stream) {
    const float* x   = (const float*)d_in[0];
    const int*   ei  = (const int*)d_in[1];
    const int*   bat = (const int*)d_in[2];
    const float* w1a = (const float*)d_in[3];  const float* b1a = (const float*)d_in[4];
    const float* w1b = (const float*)d_in[5];  const float* b1b = (const float*)d_in[6];
    const float* g1  = (const float*)d_in[7];  const float* be1 = (const float*)d_in[8];
    const float* w2a = (const float*)d_in[9];  const float* b2a = (const float*)d_in[10];
    const float* w2b = (const float*)d_in[11]; const float* b2b = (const float*)d_in[12];
    const float* g2  = (const float*)d_in[13]; const float* be2 = (const float*)d_in[14];
    const float* w3a = (const float*)d_in[15]; const float* b3a = (const float*)d_in[16];
    const float* w3b = (const float*)d_in[17]; const float* b3b = (const float*)d_in[18];
    const float* g3  = (const float*)d_in[19]; const float* be3 = (const float*)d_in[20];
    const float* wb  = (const float*)d_in[21]; const float* bb  = (const float*)d_in[22];
    const float* wm  = (const float*)d_in[23]; const float* bm  = (const float*)d_in[24];
    float* out = (float*)d_out;

    // ---- workspace layout (4-byte units) ----
    char* wsb = (char*)d_ws;
    float* hbuf    = (float*)wsb;                               // NN*DH
    float* aggbuf  = hbuf + (long)NN * DH;                      // NN*DH
    int*   csr_src = (int*)(aggbuf + (long)NN * DH);            // NE
    int*   row_ptr = csr_src + NE;                              // NN+1
    int*   cursor  = row_ptr + NN + 1;                          // NN
    int*   csum    = cursor + NN;                               // 256
    int*   gptr    = csum + 256;                                // NG+1
    float* emb     = (float*)(gptr + NG + 1);                   // NG*DH
    // zeroed region (one memset): deg[NN], ghist[NG], stats[3*64]
    int*   deg     = (int*)(emb + (long)NG * DH);               // NN
    int*   ghist   = deg + NN;                                  // NG
    float* stats1  = (float*)(ghist + NG);                      // 64
    float* stats2  = stats1 + 2 * DH;                           // 64
    float* stats3  = stats2 + 2 * DH;                           // 64
    size_t zero_bytes = ((size_t)NN + NG + 3 * 2 * DH) * 4;

    hipMemsetAsync(deg, 0, zero_bytes, stream);

    const int B = 256;
    int blkE   = (NE + B - 1) / B;
    int blkN   = (NN + B - 1) / B;
    int blkNDH = (int)(((long)NN * DH + B - 1) / B);
    int blkN8  = (int)(((long)NN * 8 + B - 1) / B);

    // ---- CSR build (reused by all 3 layers) + graph boundaries ----
    deg_hist<<<blkE, B, 0, stream>>>(ei, deg);
    ghist_kernel<<<blkN, B, 0, stream>>>(bat, ghist);
    chunk_reduce<<<NCHUNK, B, 0, stream>>>(deg, csum);
    scan_chunks<<<1, B, 0, stream>>>(csum, row_ptr);
    chunk_scan<<<NCHUNK, B, 0, stream>>>(deg, csum, row_ptr, cursor);
    gscan<<<1, B, 0, stream>>>(ghist, gptr);
    fill_csr<<<blkE, B, 0, stream>>>(ei, cursor, csr_src);

    // ---- layer 1 ----
    gather6<<<blkN, B, 0, stream>>>(row_ptr, csr_src, x, aggbuf);
    mlp_stats<DIN><<<blkN, B, 0, stream>>>(aggbuf, hbuf, w1a, b1a, w1b, b1b, stats1);
    bn_apply<<<blkNDH, B, 0, stream>>>(hbuf, stats1, g1, be1);

    // ---- layer 2 ----
    gather32<<<blkN8, B, 0, stream>>>(row_ptr, csr_src, hbuf, aggbuf);
    mlp_stats<DH><<<blkN, B, 0, stream>>>(aggbuf, hbuf, w2a, b2a, w2b, b2b, stats2);
    bn_apply<<<blkNDH, B, 0, stream>>>(hbuf, stats2, g2, be2);

    // ---- layer 3 ----
    gather32<<<blkN8, B, 0, stream>>>(row_ptr, csr_src, hbuf, aggbuf);
    mlp_stats<DH><<<blkN, B, 0, stream>>>(aggbuf, hbuf, w3a, b3a, w3b, b3b, stats3);
    bn_apply<<<blkNDH, B, 0, stream>>>(hbuf, stats3, g3, be3);

    // ---- pool + head ----
    pool2<<<NG, 64, 0, stream>>>(hbuf, gptr, emb);
    head_kernel<<<(NG + B - 1) / B, B, 0, stream>>>(emb, wb, bb, wm, bm, out);
}

// Round 3
// 809.414 us; speedup vs baseline: 9.5025x; 3.4495x over previous
//
#include <hip/hip_runtime.h>
#include <math.h>

// Problem constants (match reference)
#define NN 150000
#define NE 2400000
#define NG 1024
#define DIN 6
#define DH 32
#define DB 16
#define BN_EPS 1e-5f

#define NCHUNK ((NN + 1023) / 1024)   // 147
#define MLP_BLOCKS ((NN + 255) / 256) // 586

// ================= CSR build =================
__global__ void deg_hist(const int* __restrict__ ei, int* __restrict__ deg) {
    int e = blockIdx.x * blockDim.x + threadIdx.x;
    if (e >= NE) return;
    atomicAdd(&deg[ei[NE + e]], 1);
}

__global__ void ghist_kernel(const int* __restrict__ bat, int* __restrict__ gh) {
    int n = blockIdx.x * blockDim.x + threadIdx.x;
    if (n >= NN) return;
    atomicAdd(&gh[bat[n]], 1);
}

// per-chunk (1024 elems) sums of deg
__global__ void chunk_reduce(const int* __restrict__ deg, int* __restrict__ csum) {
    __shared__ int sd[256];
    int c = blockIdx.x, t = threadIdx.x;
    int base = c * 1024;
    int v = 0;
    for (int i = t; i < 1024; i += 256) {
        int idx = base + i;
        if (idx < NN) v += deg[idx];
    }
    sd[t] = v;
    __syncthreads();
    for (int s = 128; s > 0; s >>= 1) {
        if (t < s) sd[t] += sd[t + s];
        __syncthreads();
    }
    if (t == 0) csum[c] = sd[0];
}

// single-block exclusive scan of chunk sums (NCHUNK <= 256); also row_ptr[NN]=NE
__global__ void scan_chunks(int* __restrict__ csum, int* __restrict__ row_ptr) {
    __shared__ int s[256];
    int t = threadIdx.x;
    s[t] = (t < NCHUNK) ? csum[t] : 0;
    __syncthreads();
    for (int off = 1; off < 256; off <<= 1) {
        int val = (t >= off) ? s[t - off] : 0;
        __syncthreads();
        s[t] += val;
        __syncthreads();
    }
    if (t < NCHUNK) csum[t] = (t == 0) ? 0 : s[t - 1];
    if (t == 0) row_ptr[NN] = NE;
}

// per-chunk exclusive scan -> row_ptr + cursor copy
__global__ void chunk_scan(const int* __restrict__ deg, const int* __restrict__ cbase,
                           int* __restrict__ row_ptr, int* __restrict__ cursor) {
    __shared__ int s[256];
    int c = blockIdx.x, t = threadIdx.x;
    int idx = c * 1024 + t * 4;
    int v0 = 0, v1 = 0, v2 = 0, v3 = 0;
    if (idx + 0 < NN) v0 = deg[idx + 0];
    if (idx + 1 < NN) v1 = deg[idx + 1];
    if (idx + 2 < NN) v2 = deg[idx + 2];
    if (idx + 3 < NN) v3 = deg[idx + 3];
    int sum = v0 + v1 + v2 + v3;
    s[t] = sum;
    __syncthreads();
    for (int off = 1; off < 256; off <<= 1) {
        int val = (t >= off) ? s[t - off] : 0;
        __syncthreads();
        s[t] += val;
        __syncthreads();
    }
    int run = cbase[c] + s[t] - sum;
    if (idx + 0 < NN) { row_ptr[idx + 0] = run; cursor[idx + 0] = run; run += v0; }
    if (idx + 1 < NN) { row_ptr[idx + 1] = run; cursor[idx + 1] = run; run += v1; }
    if (idx + 2 < NN) { row_ptr[idx + 2] = run; cursor[idx + 2] = run; run += v2; }
    if (idx + 3 < NN) { row_ptr[idx + 3] = run; cursor[idx + 3] = run; run += v3; }
}

// single-block exclusive scan of graph hist (1024 = 256*4); gptr[NG]=NN
__global__ void gscan(const int* __restrict__ gh, int* __restrict__ gptr) {
    __shared__ int s[256];
    int t = threadIdx.x;
    int idx = t * 4;
    int v0 = gh[idx + 0], v1 = gh[idx + 1], v2 = gh[idx + 2], v3 = gh[idx + 3];
    int sum = v0 + v1 + v2 + v3;
    s[t] = sum;
    __syncthreads();
    for (int off = 1; off < 256; off <<= 1) {
        int val = (t >= off) ? s[t - off] : 0;
        __syncthreads();
        s[t] += val;
        __syncthreads();
    }
    int run = s[t] - sum;
    gptr[idx + 0] = run; run += v0;
    gptr[idx + 1] = run; run += v1;
    gptr[idx + 2] = run; run += v2;
    gptr[idx + 3] = run;
    if (t == 0) gptr[NG] = NN;
}

__global__ void fill_csr(const int* __restrict__ ei, int* __restrict__ cursor,
                         int* __restrict__ csr_src) {
    int e = blockIdx.x * blockDim.x + threadIdx.x;
    if (e >= NE) return;
    int s = ei[e];
    int d = ei[NE + e];
    int slot = atomicAdd(&cursor[d], 1);
    csr_src[slot] = s;
}

// ================= gather aggregation =================
// layer 1: 6 channels, 1 thread per node (3x float2 per edge)
__global__ void gather6(const int* __restrict__ row_ptr, const int* __restrict__ csr_src,
                        const float* __restrict__ x, float* __restrict__ agg) {
    int node = blockIdx.x * blockDim.x + threadIdx.x;
    if (node >= NN) return;
    int beg = row_ptr[node], end = row_ptr[node + 1];
    const float2* xs = (const float2*)(x + (long)node * DIN);
    float2 a0 = xs[0], a1 = xs[1], a2 = xs[2];   // self term
    for (int e = beg; e < end; ++e) {
        int s = csr_src[e];
        const float2* p = (const float2*)(x + (long)s * DIN);
        float2 b0 = p[0], b1 = p[1], b2 = p[2];
        a0.x += b0.x; a0.y += b0.y;
        a1.x += b1.x; a1.y += b1.y;
        a2.x += b2.x; a2.y += b2.y;
    }
    float2* o = (float2*)(agg + (long)node * DIN);
    o[0] = a0; o[1] = a1; o[2] = a2;
}

// layers 2/3: 32 channels, 8 threads per node (float4 each)
__global__ void gather32(const int* __restrict__ row_ptr, const int* __restrict__ csr_src,
                         const float* __restrict__ h, float* __restrict__ agg) {
    long tid = (long)blockIdx.x * blockDim.x + threadIdx.x;
    int node = (int)(tid >> 3);
    int t = (int)(tid & 7);
    if (node >= NN) return;
    int beg = row_ptr[node], end = row_ptr[node + 1];
    const float4* self = (const float4*)(h + (long)node * DH) + t;
    float4 acc = *self;
    for (int e = beg; e < end; ++e) {
        int s = csr_src[e];
        float4 v = *((const float4*)(h + (long)s * DH) + t);
        acc.x += v.x; acc.y += v.y; acc.z += v.z; acc.w += v.w;
    }
    *((float4*)(agg + (long)node * DH) + t) = acc;
}

// ======== fused MLP + relu + BN-stat partials (NO global atomics) ========
template <int IN>
__global__ void mlp_stats(const float* __restrict__ agg,
                          float* __restrict__ out,
                          const float* __restrict__ w1, const float* __restrict__ b1,
                          const float* __restrict__ w2, const float* __restrict__ b2,
                          float* __restrict__ partial /* [gridDim][64] */) {
    __shared__ float sw1[IN * DH];
    __shared__ float sw2[DH * DH];
    __shared__ float sb1[DH];
    __shared__ float sb2[DH];
    __shared__ float bsum[DH];
    __shared__ float bsq[DH];
    int t = threadIdx.x;
    for (int i = t; i < IN * DH; i += blockDim.x) sw1[i] = w1[i];
    for (int i = t; i < DH * DH; i += blockDim.x) sw2[i] = w2[i];
    if (t < DH) { sb1[t] = b1[t]; sb2[t] = b2[t]; bsum[t] = 0.f; bsq[t] = 0.f; }
    __syncthreads();

    int node = blockIdx.x * blockDim.x + t;
    bool valid = node < NN;

    float a[IN];
    if (valid) {
        const float* ar = agg + (long)node * IN;
#pragma unroll
        for (int k = 0; k < IN; ++k) a[k] = ar[k];
    } else {
#pragma unroll
        for (int k = 0; k < IN; ++k) a[k] = 0.f;
    }

    float u[DH];
#pragma unroll
    for (int j = 0; j < DH; ++j) {
        float acc = sb1[j];
#pragma unroll
        for (int k = 0; k < IN; ++k) acc += a[k] * sw1[k * DH + j];
        u[j] = fmaxf(acc, 0.f);
    }

    float r[DH];
#pragma unroll
    for (int j = 0; j < DH; ++j) {
        float acc = sb2[j];
#pragma unroll
        for (int k = 0; k < DH; ++k) acc += u[k] * sw2[k * DH + j];
        r[j] = valid ? fmaxf(acc, 0.f) : 0.f;
    }

    if (valid) {
        float4* o = (float4*)(out + (long)node * DH);
#pragma unroll
        for (int q = 0; q < DH / 4; ++q)
            o[q] = make_float4(r[4 * q], r[4 * q + 1], r[4 * q + 2], r[4 * q + 3]);
    }

    // wave butterfly -> LDS atomic (per block) -> one partial row per block
    int lane = t & 63;
#pragma unroll
    for (int j = 0; j < DH; ++j) {
        float s = r[j];
        float q = r[j] * r[j];
        for (int o = 32; o > 0; o >>= 1) {
            s += __shfl_xor(s, o);
            q += __shfl_xor(q, o);
        }
        if (lane == 0) {
            atomicAdd(&bsum[j], s);   // LDS atomic, cheap
            atomicAdd(&bsq[j], q);
        }
    }
    __syncthreads();
    if (t < 2 * DH) {
        float v = (t < DH) ? bsum[t] : bsq[t - DH];
        partial[(long)blockIdx.x * (2 * DH) + t] = v;
    }
}

// ===== fold partials -> BN scale/shift: ss[0..31]=sc, ss[32..63]=sh =====
__global__ void reduce_stats(const float* __restrict__ partial, int nblk,
                             const float* __restrict__ g, const float* __restrict__ be,
                             float* __restrict__ ss) {
    __shared__ float sums[2 * DH];
    int t = threadIdx.x;          // 256
    int ch = t >> 2, k0 = t & 3;
    float acc = 0.f;
    for (int k = k0; k < nblk; k += 4) acc += partial[(long)k * (2 * DH) + ch];
    acc += __shfl_xor(acc, 1);
    acc += __shfl_xor(acc, 2);
    if (k0 == 0) sums[ch] = acc;
    __syncthreads();
    if (t < DH) {
        float mu = sums[t] * (1.0f / NN);
        float var = sums[DH + t] * (1.0f / NN) - mu * mu;
        float sc = g[t] * rsqrtf(var + BN_EPS);
        ss[t] = sc;
        ss[DH + t] = be[t] - mu * sc;
    }
}

// ================= BN apply (in place, affine, float4 x2) =================
__global__ void bn_apply(float* __restrict__ h, const float* __restrict__ ss) {
    int tid = blockIdx.x * blockDim.x + threadIdx.x;   // NN*4 threads
    if (tid >= NN * 4) return;
    int d0 = (tid & 3) * 8;
    float4* p = (float4*)(h + (long)(tid >> 2) * DH + d0);
    float4 a = p[0], b = p[1];
    a.x = a.x * ss[d0 + 0] + ss[DH + d0 + 0];
    a.y = a.y * ss[d0 + 1] + ss[DH + d0 + 1];
    a.z = a.z * ss[d0 + 2] + ss[DH + d0 + 2];
    a.w = a.w * ss[d0 + 3] + ss[DH + d0 + 3];
    b.x = b.x * ss[d0 + 4] + ss[DH + d0 + 4];
    b.y = b.y * ss[d0 + 5] + ss[DH + d0 + 5];
    b.z = b.z * ss[d0 + 6] + ss[DH + d0 + 6];
    b.w = b.w * ss[d0 + 7] + ss[DH + d0 + 7];
    p[0] = a; p[1] = b;
}

// ================= per-graph mean pool (no atomics; batch is sorted) =================
__global__ void pool2(const float* __restrict__ h, const int* __restrict__ gptr,
                      float* __restrict__ emb) {
    int g = blockIdx.x;
    int t = threadIdx.x;           // 64 threads
    int beg = gptr[g], end = gptr[g + 1];
    int d = t & 31, half = t >> 5;
    float acc = 0.f;
    for (int n = beg + half; n < end; n += 2) acc += h[(long)n * DH + d];
    acc += __shfl_xor(acc, 32);
    if (t < 32) {
        float cnt = (float)(end - beg);
        emb[(long)g * DH + d] = acc / fmaxf(cnt, 1.0f);
    }
}

// ================= head: emb -> 16 relu -> 1 sigmoid =================
__global__ void head_kernel(const float* __restrict__ emb,
                            const float* __restrict__ wb, const float* __restrict__ bb,
                            const float* __restrict__ wm, const float* __restrict__ bm,
                            float* __restrict__ out) {
    __shared__ float swb[DH * DB];
    __shared__ float sbb[DB];
    __shared__ float swm[DB];
    int t = threadIdx.x;
    for (int i = t; i < DH * DB; i += blockDim.x) swb[i] = wb[i];
    if (t < DB) { sbb[t] = bb[t]; swm[t] = wm[t]; }
    __syncthreads();

    int g = blockIdx.x * blockDim.x + t;
    if (g >= NG) return;
    float e[DH];
#pragma unroll
    for (int d = 0; d < DH; ++d) e[d] = emb[(long)g * DH + d];
    float acc = bm[0];
#pragma unroll
    for (int j = 0; j < DB; ++j) {
        float z = sbb[j];
#pragma unroll
        for (int d = 0; d < DH; ++d) z += e[d] * swb[d * DB + j];
        z = fmaxf(z, 0.f);
        acc += z * swm[j];
    }
    out[g] = 1.0f / (1.0f + expf(-acc));
}

extern "C" void kernel_launch(void* const* d_in, const int* in_sizes, int n_in,
                              void* d_out, int out_size, void* d_ws, size_t ws_size,
                              hipStream_t stream) {
    const float* x   = (const float*)d_in[0];
    const int*   ei  = (const int*)d_in[1];
    const int*   bat = (const int*)d_in[2];
    const float* w1a = (const float*)d_in[3];  const float* b1a = (const float*)d_in[4];
    const float* w1b = (const float*)d_in[5];  const float* b1b = (const float*)d_in[6];
    const float* g1  = (const float*)d_in[7];  const float* be1 = (const float*)d_in[8];
    const float* w2a = (const float*)d_in[9];  const float* b2a = (const float*)d_in[10];
    const float* w2b = (const float*)d_in[11]; const float* b2b = (const float*)d_in[12];
    const float* g2  = (const float*)d_in[13]; const float* be2 = (const float*)d_in[14];
    const float* w3a = (const float*)d_in[15]; const float* b3a = (const float*)d_in[16];
    const float* w3b = (const float*)d_in[17]; const float* b3b = (const float*)d_in[18];
    const float* g3  = (const float*)d_in[19]; const float* be3 = (const float*)d_in[20];
    const float* wb  = (const float*)d_in[21]; const float* bb  = (const float*)d_in[22];
    const float* wm  = (const float*)d_in[23]; const float* bm  = (const float*)d_in[24];
    float* out = (float*)d_out;

    // ---- workspace layout (4-byte units) ----
    char* wsb = (char*)d_ws;
    float* hbuf    = (float*)wsb;                               // NN*DH
    float* aggbuf  = hbuf + (long)NN * DH;                      // NN*DH
    int*   csr_src = (int*)(aggbuf + (long)NN * DH);            // NE
    int*   row_ptr = csr_src + NE;                              // NN+1
    int*   cursor  = row_ptr + NN + 1;                          // NN
    int*   csum    = cursor + NN;                               // 256
    int*   gptr    = csum + 256;                                // NG+1
    float* emb     = (float*)(gptr + NG + 1);                   // NG*DH
    float* ss1     = emb + (long)NG * DH;                       // 64 (BN scale/shift)
    float* ss2     = ss1 + 2 * DH;                              // 64
    float* ss3     = ss2 + 2 * DH;                              // 64
    float* partial = ss3 + 2 * DH;                              // MLP_BLOCKS*64
    // zeroed region (one memset): deg[NN], ghist[NG]
    int*   deg     = (int*)(partial + (long)MLP_BLOCKS * 2 * DH); // NN
    int*   ghist   = deg + NN;                                  // NG
    size_t zero_bytes = ((size_t)NN + NG) * 4;

    hipMemsetAsync(deg, 0, zero_bytes, stream);

    const int B = 256;
    int blkE   = (NE + B - 1) / B;
    int blkN   = (NN + B - 1) / B;       // == MLP_BLOCKS
    int blkN4  = (int)(((long)NN * 4 + B - 1) / B);
    int blkN8  = (int)(((long)NN * 8 + B - 1) / B);

    // ---- CSR build (reused by all 3 layers) + graph boundaries ----
    deg_hist<<<blkE, B, 0, stream>>>(ei, deg);
    ghist_kernel<<<blkN, B, 0, stream>>>(bat, ghist);
    chunk_reduce<<<NCHUNK, B, 0, stream>>>(deg, csum);
    scan_chunks<<<1, B, 0, stream>>>(csum, row_ptr);
    chunk_scan<<<NCHUNK, B, 0, stream>>>(deg, csum, row_ptr, cursor);
    gscan<<<1, B, 0, stream>>>(ghist, gptr);
    fill_csr<<<blkE, B, 0, stream>>>(ei, cursor, csr_src);

    // ---- layer 1 ----
    gather6<<<blkN, B, 0, stream>>>(row_ptr, csr_src, x, aggbuf);
    mlp_stats<DIN><<<blkN, B, 0, stream>>>(aggbuf, hbuf, w1a, b1a, w1b, b1b, partial);
    reduce_stats<<<1, B, 0, stream>>>(partial, blkN, g1, be1, ss1);
    bn_apply<<<blkN4, B, 0, stream>>>(hbuf, ss1);

    // ---- layer 2 ----
    gather32<<<blkN8, B, 0, stream>>>(row_ptr, csr_src, hbuf, aggbuf);
    mlp_stats<DH><<<blkN, B, 0, stream>>>(aggbuf, hbuf, w2a, b2a, w2b, b2b, partial);
    reduce_stats<<<1, B, 0, stream>>>(partial, blkN, g2, be2, ss2);
    bn_apply<<<blkN4, B, 0, stream>>>(hbuf, ss2);

    // ---- layer 3 ----
    gather32<<<blkN8, B, 0, stream>>>(row_ptr, csr_src, hbuf, aggbuf);
    mlp_stats<DH><<<blkN, B, 0, stream>>>(aggbuf, hbuf, w3a, b3a, w3b, b3b, partial);
    reduce_stats<<<1, B, 0, stream>>>(partial, blkN, g3, be3, ss3);
    bn_apply<<<blkN4, B, 0, stream>>>(hbuf, ss3);

    // ---- pool + head ----
    pool2<<<NG, 64, 0, stream>>>(hbuf, gptr, emb);
    head_kernel<<<(NG + B - 1) / B, B, 0, stream>>>(emb, wb, bb, wm, bm, out);
}

// Round 4
// 552.405 us; speedup vs baseline: 13.9236x; 1.4653x over previous
//
#include <hip/hip_runtime.h>
#include <math.h>

// Problem constants (match reference)
#define NN 150000
#define NE 2400000
#define NG 1024
#define DIN 6
#define DH 32
#define DB 16
#define BN_EPS 1e-5f

#define MLP_BLOCKS ((NN + 255) / 256) // 586

// bucket sort params
#define NB 512            // buckets
#define NPB 293           // nodes per bucket (512*293 = 150016 >= NN)
#define SCH 4096          // edges per scatter block
#define EPB 16            // edges per thread in scatter
#define CAP 8192          // max edges per bucket (expected ~4690)
#define NSCAT ((NE + SCH - 1) / SCH)  // 586

// inclusive Hillis-Steele scan of 512 ints in LDS with 256 threads
#define SCAN512(scarr, t)                                     \
    for (int off = 1; off < 512; off <<= 1) {                 \
        int v0 = (t >= off) ? scarr[t - off] : 0;             \
        int v1 = scarr[t + 256 - off];                        \
        __syncthreads();                                      \
        if (t >= off) scarr[t] += v0;                         \
        scarr[t + 256] += v1;                                 \
        __syncthreads();                                      \
    }

// ================= bucket CSR build =================
__global__ void bucket_count(const int* __restrict__ ei, int* __restrict__ bcnt) {
    __shared__ int hist[NB];
    int t = threadIdx.x;
    for (int i = t; i < NB; i += 256) hist[i] = 0;
    __syncthreads();
    long e0 = (long)blockIdx.x * SCH;
#pragma unroll
    for (int k = 0; k < EPB; ++k) {
        long idx = e0 + k * 256 + t;
        if (idx < NE) atomicAdd(&hist[ei[NE + idx] / NPB], 1);
    }
    __syncthreads();
    for (int i = t; i < NB; i += 256)
        if (hist[i]) atomicAdd(&bcnt[i], hist[i]);
}

__global__ void bucket_scan(const int* __restrict__ bcnt,
                            int* __restrict__ bbase, int* __restrict__ bcur) {
    __shared__ int sc[NB];
    int t = threadIdx.x;
    int c0 = bcnt[t], c1 = bcnt[t + 256];
    sc[t] = c0; sc[t + 256] = c1;
    __syncthreads();
    SCAN512(sc, t);
    int e0 = sc[t] - c0, e1 = sc[t + 256] - c1;
    bbase[t] = e0; bbase[t + 256] = e1;
    bcur[t] = e0;  bcur[t + 256] = e1;
    if (t == 0) bbase[NB] = NE;
}

// block-local binning -> semi-coalesced (src,dst) writes into bucket regions
__global__ void bucket_scatter(const int* __restrict__ ei, int* __restrict__ bcur,
                               uint2* __restrict__ ebuf) {
    __shared__ int hist[NB];
    __shared__ int sc[NB];
    __shared__ int lcur[NB];
    __shared__ int gbase[NB];
    __shared__ uint2 stage[SCH];
    int t = threadIdx.x;
    long e0 = (long)blockIdx.x * SCH;
    int s16[EPB], d16[EPB];
    for (int i = t; i < NB; i += 256) hist[i] = 0;
    __syncthreads();
#pragma unroll
    for (int k = 0; k < EPB; ++k) {
        long idx = e0 + k * 256 + t;
        if (idx < NE) {
            s16[k] = ei[idx];
            d16[k] = ei[NE + idx];
            atomicAdd(&hist[d16[k] / NPB], 1);
        } else d16[k] = -1;
    }
    __syncthreads();
    for (int i = t; i < NB; i += 256) sc[i] = hist[i];
    __syncthreads();
    SCAN512(sc, t);
    for (int i = t; i < NB; i += 256) lcur[i] = sc[i] - hist[i];
    __syncthreads();
#pragma unroll
    for (int k = 0; k < EPB; ++k) {
        if (d16[k] >= 0) {
            int b = d16[k] / NPB;
            int p = atomicAdd(&lcur[b], 1);
            stage[p] = make_uint2((unsigned)s16[k], (unsigned)d16[k]);
        }
    }
    __syncthreads();
    for (int i = t; i < NB; i += 256) {
        int h = hist[i];
        gbase[i] = h ? atomicAdd(&bcur[i], h) : 0;
    }
    __syncthreads();
    int cnt = (int)((NE - e0) < SCH ? (NE - e0) : SCH);
    for (int i = t; i < cnt; i += 256) {
        uint2 ed = stage[i];
        int b = (int)ed.y / NPB;
        ebuf[gbase[b] + (i - (sc[b] - hist[b]))] = ed;
    }
}

// per-bucket LDS counting sort -> csr_src + row_ptr (fully coalesced global I/O)
__global__ void bucket_sort(const uint2* __restrict__ ebuf, const int* __restrict__ bbase,
                            int* __restrict__ row_ptr, int* __restrict__ csr_src) {
    __shared__ int deg[NB];
    __shared__ int sc[NB];
    __shared__ int cur[NB];
    __shared__ int srcbuf[CAP];
    int b = blockIdx.x, t = threadIdx.x;
    int node0 = b * NPB;
    int nlocal = (NN - node0) < NPB ? (NN - node0) : NPB;
    int ebase = bbase[b];
    int ecnt = bbase[b + 1] - ebase;
    if (ecnt > CAP) ecnt = CAP;
    for (int i = t; i < NB; i += 256) deg[i] = 0;
    __syncthreads();
    for (int i = t; i < ecnt; i += 256) {
        int d = (int)ebuf[ebase + i].y - node0;
        atomicAdd(&deg[d], 1);
    }
    __syncthreads();
    for (int i = t; i < NB; i += 256) sc[i] = deg[i];
    __syncthreads();
    SCAN512(sc, t);
    for (int j = t; j < nlocal; j += 256) {
        int st = sc[j] - deg[j];
        row_ptr[node0 + j] = ebase + st;
        cur[j] = st;
    }
    if (b == NB - 1 && t == 0) row_ptr[NN] = NE;
    __syncthreads();
    for (int i = t; i < ecnt; i += 256) {
        uint2 ed = ebuf[ebase + i];
        int d = (int)ed.y - node0;
        int p = atomicAdd(&cur[d], 1);
        srcbuf[p] = (int)ed.x;
    }
    __syncthreads();
    for (int i = t; i < ecnt; i += 256) csr_src[ebase + i] = srcbuf[i];
}

// ================= graph boundaries =================
__global__ void ghist_kernel(const int* __restrict__ bat, int* __restrict__ gh) {
    int n = blockIdx.x * blockDim.x + threadIdx.x;
    if (n >= NN) return;
    atomicAdd(&gh[bat[n]], 1);
}

__global__ void gscan(const int* __restrict__ gh, int* __restrict__ gptr) {
    __shared__ int s[256];
    int t = threadIdx.x;
    int idx = t * 4;
    int v0 = gh[idx + 0], v1 = gh[idx + 1], v2 = gh[idx + 2], v3 = gh[idx + 3];
    int sum = v0 + v1 + v2 + v3;
    s[t] = sum;
    __syncthreads();
    for (int off = 1; off < 256; off <<= 1) {
        int val = (t >= off) ? s[t - off] : 0;
        __syncthreads();
        s[t] += val;
        __syncthreads();
    }
    int run = s[t] - sum;
    gptr[idx + 0] = run; run += v0;
    gptr[idx + 1] = run; run += v1;
    gptr[idx + 2] = run; run += v2;
    gptr[idx + 3] = run;
    if (t == 0) gptr[NG] = NN;
}

// ================= gather aggregation =================
// layer 1: 6 channels, 1 thread per node
__global__ void gather6(const int* __restrict__ row_ptr, const int* __restrict__ csr_src,
                        const float* __restrict__ x, float* __restrict__ agg) {
    int node = blockIdx.x * blockDim.x + threadIdx.x;
    if (node >= NN) return;
    int beg = row_ptr[node], end = row_ptr[node + 1];
    const float2* xs = (const float2*)(x + (long)node * DIN);
    float2 a0 = xs[0], a1 = xs[1], a2 = xs[2];   // self term
    for (int e = beg; e < end; ++e) {
        int s = csr_src[e];
        const float2* p = (const float2*)(x + (long)s * DIN);
        float2 b0 = p[0], b1 = p[1], b2 = p[2];
        a0.x += b0.x; a0.y += b0.y;
        a1.x += b1.x; a1.y += b1.y;
        a2.x += b2.x; a2.y += b2.y;
    }
    float2* o = (float2*)(agg + (long)node * DIN);
    o[0] = a0; o[1] = a1; o[2] = a2;
}

// layers 2/3: gather of BN(h) with BN folded as affine:
// sum(sc*h+sh) over {self + neighbors} = sc*sum(h) + cnt*sh
__global__ void gather32_aff(const int* __restrict__ row_ptr, const int* __restrict__ csr_src,
                             const float* __restrict__ h, const float* __restrict__ ss,
                             float* __restrict__ agg) {
    long tid = (long)blockIdx.x * blockDim.x + threadIdx.x;
    int node = (int)(tid >> 3);
    int t = (int)(tid & 7);
    if (node >= NN) return;
    int beg = row_ptr[node], end = row_ptr[node + 1];
    float4 acc = *((const float4*)(h + (long)node * DH) + t);
    for (int e = beg; e < end; ++e) {
        int s = csr_src[e];
        float4 v = *((const float4*)(h + (long)s * DH) + t);
        acc.x += v.x; acc.y += v.y; acc.z += v.z; acc.w += v.w;
    }
    float cnt = (float)(end - beg + 1);
    float4 scv = *((const float4*)ss + t);
    float4 shv = *((const float4*)(ss + DH) + t);
    float4 o;
    o.x = acc.x * scv.x + cnt * shv.x;
    o.y = acc.y * scv.y + cnt * shv.y;
    o.z = acc.z * scv.z + cnt * shv.z;
    o.w = acc.w * scv.w + cnt * shv.w;
    *((float4*)(agg + (long)node * DH) + t) = o;
}

// ======== fused MLP + relu + BN-stat partials (NO global atomics) ========
template <int IN>
__global__ void mlp_stats(const float* __restrict__ agg,
                          float* __restrict__ out,
                          const float* __restrict__ w1, const float* __restrict__ b1,
                          const float* __restrict__ w2, const float* __restrict__ b2,
                          float* __restrict__ partial /* [gridDim][64] */) {
    __shared__ float sw1[IN * DH];
    __shared__ float sw2[DH * DH];
    __shared__ float sb1[DH];
    __shared__ float sb2[DH];
    __shared__ float bsum[DH];
    __shared__ float bsq[DH];
    int t = threadIdx.x;
    for (int i = t; i < IN * DH; i += blockDim.x) sw1[i] = w1[i];
    for (int i = t; i < DH * DH; i += blockDim.x) sw2[i] = w2[i];
    if (t < DH) { sb1[t] = b1[t]; sb2[t] = b2[t]; bsum[t] = 0.f; bsq[t] = 0.f; }
    __syncthreads();

    int node = blockIdx.x * blockDim.x + t;
    bool valid = node < NN;

    float a[IN];
    if (valid) {
        const float* ar = agg + (long)node * IN;
#pragma unroll
        for (int k = 0; k < IN; ++k) a[k] = ar[k];
    } else {
#pragma unroll
        for (int k = 0; k < IN; ++k) a[k] = 0.f;
    }

    float u[DH];
#pragma unroll
    for (int j = 0; j < DH; ++j) {
        float acc = sb1[j];
#pragma unroll
        for (int k = 0; k < IN; ++k) acc += a[k] * sw1[k * DH + j];
        u[j] = fmaxf(acc, 0.f);
    }

    float r[DH];
#pragma unroll
    for (int j = 0; j < DH; ++j) {
        float acc = sb2[j];
#pragma unroll
        for (int k = 0; k < DH; ++k) acc += u[k] * sw2[k * DH + j];
        r[j] = valid ? fmaxf(acc, 0.f) : 0.f;
    }

    if (valid) {
        float4* o = (float4*)(out + (long)node * DH);
#pragma unroll
        for (int q = 0; q < DH / 4; ++q)
            o[q] = make_float4(r[4 * q], r[4 * q + 1], r[4 * q + 2], r[4 * q + 3]);
    }

    int lane = t & 63;
#pragma unroll
    for (int j = 0; j < DH; ++j) {
        float s = r[j];
        float q = r[j] * r[j];
        for (int o = 32; o > 0; o >>= 1) {
            s += __shfl_xor(s, o);
            q += __shfl_xor(q, o);
        }
        if (lane == 0) {
            atomicAdd(&bsum[j], s);   // LDS atomic, cheap
            atomicAdd(&bsq[j], q);
        }
    }
    __syncthreads();
    if (t < 2 * DH) {
        float v = (t < DH) ? bsum[t] : bsq[t - DH];
        partial[(long)blockIdx.x * (2 * DH) + t] = v;
    }
}

// ===== fold partials -> BN scale/shift: ss[0..31]=sc, ss[32..63]=sh =====
__global__ void reduce_stats(const float* __restrict__ partial, int nblk,
                             const float* __restrict__ g, const float* __restrict__ be,
                             float* __restrict__ ss) {
    __shared__ float sums[2 * DH];
    int t = threadIdx.x;          // 256
    int ch = t >> 2, k0 = t & 3;
    float acc = 0.f;
    for (int k = k0; k < nblk; k += 4) acc += partial[(long)k * (2 * DH) + ch];
    acc += __shfl_xor(acc, 1);
    acc += __shfl_xor(acc, 2);
    if (k0 == 0) sums[ch] = acc;
    __syncthreads();
    if (t < DH) {
        float mu = sums[t] * (1.0f / NN);
        float var = sums[DH + t] * (1.0f / NN) - mu * mu;
        float sc = g[t] * rsqrtf(var + BN_EPS);
        ss[t] = sc;
        ss[DH + t] = be[t] - mu * sc;
    }
}

// ====== per-graph mean pool of BN(h), affine folded: sc*mean(h)+sh ======
__global__ void pool2_aff(const float* __restrict__ h, const int* __restrict__ gptr,
                          const float* __restrict__ ss, float* __restrict__ emb) {
    int g = blockIdx.x;
    int t = threadIdx.x;           // 64 threads
    int beg = gptr[g], end = gptr[g + 1];
    int d = t & 31, half = t >> 5;
    float acc = 0.f;
    for (int n = beg + half; n < end; n += 2) acc += h[(long)n * DH + d];
    acc += __shfl_xor(acc, 32);
    if (t < 32) {
        int c = end - beg;
        float val = 0.f;
        if (c > 0) val = ss[d] * (acc / (float)c) + ss[DH + d];
        emb[(long)g * DH + d] = val;
    }
}

// ================= head: emb -> 16 relu -> 1 sigmoid =================
__global__ void head_kernel(const float* __restrict__ emb,
                            const float* __restrict__ wb, const float* __restrict__ bb,
                            const float* __restrict__ wm, const float* __restrict__ bm,
                            float* __restrict__ out) {
    __shared__ float swb[DH * DB];
    __shared__ float sbb[DB];
    __shared__ float swm[DB];
    int t = threadIdx.x;
    for (int i = t; i < DH * DB; i += blockDim.x) swb[i] = wb[i];
    if (t < DB) { sbb[t] = bb[t]; swm[t] = wm[t]; }
    __syncthreads();

    int g = blockIdx.x * blockDim.x + t;
    if (g >= NG) return;
    float e[DH];
#pragma unroll
    for (int d = 0; d < DH; ++d) e[d] = emb[(long)g * DH + d];
    float acc = bm[0];
#pragma unroll
    for (int j = 0; j < DB; ++j) {
        float z = sbb[j];
#pragma unroll
        for (int d = 0; d < DH; ++d) z += e[d] * swb[d * DB + j];
        z = fmaxf(z, 0.f);
        acc += z * swm[j];
    }
    out[g] = 1.0f / (1.0f + expf(-acc));
}

extern "C" void kernel_launch(void* const* d_in, const int* in_sizes, int n_in,
                              void* d_out, int out_size, void* d_ws, size_t ws_size,
                              hipStream_t stream) {
    const float* x   = (const float*)d_in[0];
    const int*   ei  = (const int*)d_in[1];
    const int*   bat = (const int*)d_in[2];
    const float* w1a = (const float*)d_in[3];  const float* b1a = (const float*)d_in[4];
    const float* w1b = (const float*)d_in[5];  const float* b1b = (const float*)d_in[6];
    const float* g1  = (const float*)d_in[7];  const float* be1 = (const float*)d_in[8];
    const float* w2a = (const float*)d_in[9];  const float* b2a = (const float*)d_in[10];
    const float* w2b = (const float*)d_in[11]; const float* b2b = (const float*)d_in[12];
    const float* g2  = (const float*)d_in[13]; const float* be2 = (const float*)d_in[14];
    const float* w3a = (const float*)d_in[15]; const float* b3a = (const float*)d_in[16];
    const float* w3b = (const float*)d_in[17]; const float* b3b = (const float*)d_in[18];
    const float* g3  = (const float*)d_in[19]; const float* be3 = (const float*)d_in[20];
    const float* wb  = (const float*)d_in[21]; const float* bb  = (const float*)d_in[22];
    const float* wm  = (const float*)d_in[23]; const float* bm  = (const float*)d_in[24];
    float* out = (float*)d_out;

    // ---- workspace layout (4-byte units) ----
    char* wsb = (char*)d_ws;
    float* hbuf    = (float*)wsb;                               // NN*DH
    float* aggbuf  = hbuf + (long)NN * DH;                      // NN*DH  (aliased as ebuf: NE uint2 = same bytes)
    uint2* ebuf    = (uint2*)aggbuf;
    int*   csr_src = (int*)(aggbuf + (long)NN * DH);            // NE
    int*   row_ptr = csr_src + NE;                              // NN+1
    int*   bbase   = row_ptr + NN + 1;                          // NB+1
    int*   bcur    = bbase + NB + 1;                            // NB
    int*   gptr    = bcur + NB;                                 // NG+1
    float* emb     = (float*)(gptr + NG + 1);                   // NG*DH
    float* ss1     = emb + (long)NG * DH;                       // 64 (BN scale/shift)
    float* ss2     = ss1 + 2 * DH;                              // 64
    float* ss3     = ss2 + 2 * DH;                              // 64
    float* partial = ss3 + 2 * DH;                              // MLP_BLOCKS*64
    // zeroed region (one memset): ghist[NG], bcnt[NB]
    int*   ghist   = (int*)(partial + (long)MLP_BLOCKS * 2 * DH); // NG
    int*   bcnt    = ghist + NG;                                // NB
    size_t zero_bytes = ((size_t)NG + NB) * 4;

    hipMemsetAsync(ghist, 0, zero_bytes, stream);

    const int B = 256;
    int blkN  = (NN + B - 1) / B;       // == MLP_BLOCKS
    int blkN8 = (int)(((long)NN * 8 + B - 1) / B);

    // ---- CSR via two-level bucket sort (all random access in LDS) ----
    bucket_count<<<NSCAT, B, 0, stream>>>(ei, bcnt);
    ghist_kernel<<<blkN, B, 0, stream>>>(bat, ghist);
    bucket_scan<<<1, B, 0, stream>>>(bcnt, bbase, bcur);
    gscan<<<1, B, 0, stream>>>(ghist, gptr);
    bucket_scatter<<<NSCAT, B, 0, stream>>>(ei, bcur, ebuf);
    bucket_sort<<<NB, B, 0, stream>>>(ebuf, bbase, row_ptr, csr_src);

    // ---- layer 1 ----  (aggbuf free again after bucket_sort)
    gather6<<<blkN, B, 0, stream>>>(row_ptr, csr_src, x, aggbuf);
    mlp_stats<DIN><<<blkN, B, 0, stream>>>(aggbuf, hbuf, w1a, b1a, w1b, b1b, partial);
    reduce_stats<<<1, B, 0, stream>>>(partial, blkN, g1, be1, ss1);

    // ---- layer 2 ---- (BN1 applied inline in gather)
    gather32_aff<<<blkN8, B, 0, stream>>>(row_ptr, csr_src, hbuf, ss1, aggbuf);
    mlp_stats<DH><<<blkN, B, 0, stream>>>(aggbuf, hbuf, w2a, b2a, w2b, b2b, partial);
    reduce_stats<<<1, B, 0, stream>>>(partial, blkN, g2, be2, ss2);

    // ---- layer 3 ----
    gather32_aff<<<blkN8, B, 0, stream>>>(row_ptr, csr_src, hbuf, ss2, aggbuf);
    mlp_stats<DH><<<blkN, B, 0, stream>>>(aggbuf, hbuf, w3a, b3a, w3b, b3b, partial);
    reduce_stats<<<1, B, 0, stream>>>(partial, blkN, g3, be3, ss3);

    // ---- pool (BN3 applied inline) + head ----
    pool2_aff<<<NG, 64, 0, stream>>>(hbuf, gptr, ss3, emb);
    head_kernel<<<(NG + B - 1) / B, B, 0, stream>>>(emb, wb, bb, wm, bm, out);
}